// Round 2
// baseline (210.187 us; speedup 1.0000x reference)
//
#include <hip/hip_runtime.h>

#define LOG2E 1.44269504088896f

typedef _Float16 half8  __attribute__((ext_vector_type(8)));
typedef _Float16 half4v __attribute__((ext_vector_type(4)));
typedef float    floatx4 __attribute__((ext_vector_type(4)));

__device__ __forceinline__ floatx4 mfma16(half8 a, half8 b, floatx4 c) {
    return __builtin_amdgcn_mfma_f32_16x16x32_f16(a, b, c, 0, 0, 0);
}

// sigmoid(d) = 1/(1+exp(-d)); saturates cleanly to 0/1 for |d| large
__device__ __forceinline__ float sigmf(float d) {
    return __builtin_amdgcn_rcpf(1.0f + __builtin_amdgcn_exp2f(d * (-LOG2E)));
}

// Load K[gidx][0][:] - K[gidx][1][:] (16 of 64 dims, per `part`) as fp16 into sB row j
__device__ __forceinline__ void store_kdiff(_Float16* dst, const float* __restrict__ tkey,
                                            int j, int part, int gidx, bool valid)
{
    half8 h0, h1;
    if (valid) {
        const floatx4* kp = (const floatx4*)(tkey + (size_t)gidx * 128);
        floatx4 a0 = kp[part * 4 + 0], a1 = kp[part * 4 + 1];
        floatx4 a2 = kp[part * 4 + 2], a3 = kp[part * 4 + 3];
        floatx4 b0 = kp[16 + part * 4 + 0], b1 = kp[16 + part * 4 + 1];
        floatx4 b2 = kp[16 + part * 4 + 2], b3 = kp[16 + part * 4 + 3];
        #pragma unroll
        for (int e = 0; e < 4; ++e) {
            h0[e]     = (_Float16)(a0[e] - b0[e]);
            h0[4 + e] = (_Float16)(a1[e] - b1[e]);
            h1[e]     = (_Float16)(a2[e] - b2[e]);
            h1[4 + e] = (_Float16)(a3[e] - b3[e]);
        }
    } else {
        #pragma unroll
        for (int e = 0; e < 8; ++e) { h0[e] = (_Float16)0.f; h1[e] = (_Float16)0.f; }
    }
    *(half8*)(dst + j * 72 + part * 16)     = h0;
    *(half8*)(dst + j * 72 + part * 16 + 8) = h1;
}

#define PSTRIDE 136  // node-prob row stride: 128 batch cols + 8 pad

// Fused tree attention.
// grid = 1024 blocks: blockIdx = g*16 + tb, g = depth-6 leaf group (0..63), tb = batch tile (0..15).
// Each block: 128 batch rows x 1024 leaves (16 subtrees of 64 leaves), partial O -> ws (or atomic).
__global__ __launch_bounds__(256, 2)
void tree_attn(const float* __restrict__ q,
               const float* __restrict__ tkey,
               const float* __restrict__ tval,
               float* __restrict__ outp,
               int use_atomic)
{
    __shared__ _Float16 sA[128 * 72];        // fp16 q tile, later leaf probs (A-operand)
    __shared__ _Float16 sB[64 * 72];         // fp16 kdiff (B-operand)
    __shared__ _Float16 sV[64 * 72];         // fp16 V^T [v][l] (B-operand)
    __shared__ float    sP0[16 * 128];       // subtree prefix probs [s_local][b]
    __shared__ _Float16 sProb[64 * PSTRIDE]; // node probs [node][b]  (b = 0..127)

    const int tid  = threadIdx.x;
    const int w    = tid >> 6;
    const int lane = tid & 63;
    const int lm   = lane & 15;
    const int quad = lane >> 4;
    const int g    = blockIdx.x >> 4;
    const int tb   = blockIdx.x & 15;

    // ---------- stage q tile (128 x 64 fp32 -> fp16 in sA) ----------
    {
        const int r = tid >> 1, hh = tid & 1;
        const floatx4* qp = (const floatx4*)(q + (size_t)(tb * 128 + r) * 64 + hh * 32);
        #pragma unroll
        for (int t = 0; t < 4; ++t) {
            floatx4 f0 = qp[2 * t], f1 = qp[2 * t + 1];
            half8 hv;
            #pragma unroll
            for (int e = 0; e < 4; ++e) { hv[e] = (_Float16)f0[e]; hv[4 + e] = (_Float16)f1[e]; }
            *(half8*)(sA + r * 72 + hh * 32 + t * 8) = hv;
        }
    }

    // ---------- stage prefix kdiff: 21 nodes (path depths 0..5 + depth6..9 subtree) ----------
    {
        const int j = tid >> 2, part = tid & 3;
        int gidx = 0; bool valid = false;
        if (j < 6) {                       // ancestors of group g at depths 0..5
            valid = true; gidx = (1 << j) - 1 + (g >> (6 - j));
        } else if (j < 21) {               // depth-6..9 subtree rooted at node g
            int u = j - 5;
            int e = 31 - __builtin_clz(u);
            int i = u - (1 << e);
            valid = true; gidx = ((1 << (6 + e)) - 1) + (g << e) + i;
        }
        store_kdiff(sB, tkey, j, part, gidx, valid);
    }
    __syncthreads();

    // ---------- q A-fragments (persist in regs) ----------
    half8 qA[2][2];
    #pragma unroll
    for (int m = 0; m < 2; ++m)
        #pragma unroll
        for (int kt = 0; kt < 2; ++kt)
            qA[m][kt] = *(const half8*)(sA + (32 * w + 16 * m + lm) * 72 + 32 * kt + 8 * quad);

    // ---------- prefix GEMM1 + sigmoid -> node probs ----------
    {
        floatx4 acc[2][4];
        #pragma unroll
        for (int m = 0; m < 2; ++m)
            #pragma unroll
            for (int nt = 0; nt < 4; ++nt) { acc[m][nt][0]=0.f; acc[m][nt][1]=0.f; acc[m][nt][2]=0.f; acc[m][nt][3]=0.f; }
        #pragma unroll
        for (int nt = 0; nt < 4; ++nt)
            #pragma unroll
            for (int kt = 0; kt < 2; ++kt) {
                half8 bf = *(const half8*)(sB + (16 * nt + lm) * 72 + 32 * kt + 8 * quad);
                acc[0][nt] = mfma16(qA[0][kt], bf, acc[0][nt]);
                acc[1][nt] = mfma16(qA[1][kt], bf, acc[1][nt]);
            }
        // D[row=4*quad+r][col=lm]: node = 16*nt+lm, batch-in-tile = 32*w+16*m+4*quad+r
        #pragma unroll
        for (int m = 0; m < 2; ++m)
            #pragma unroll
            for (int nt = 0; nt < 4; ++nt) {
                half4v ph;
                #pragma unroll
                for (int r = 0; r < 4; ++r) ph[r] = (_Float16)sigmf(acc[m][nt][r]);
                *(half4v*)(sProb + (16 * nt + lm) * PSTRIDE + 32 * w + 16 * m + 4 * quad) = ph;
            }
    }
    __syncthreads();

    // ---------- prefix probs P0[s_local][b] ----------
    {
        const int b = tid & 127, h2 = tid >> 7;
        float pref = 1.f;
        #pragma unroll
        for (int d = 0; d < 6; ++d) {
            float pv = (float)sProb[d * PSTRIDE + b];
            pref *= ((g >> (5 - d)) & 1) ? (1.f - pv) : pv;
        }
        for (int sl = 8 * h2; sl < 8 * h2 + 8; ++sl) {
            const int a0 = sl >> 3, a1 = sl >> 2, a2 = sl >> 1;
            float P = pref, pv;
            pv = (float)sProb[6 * PSTRIDE + b];        P *= a0       ? (1.f - pv) : pv;
            pv = (float)sProb[(7 + a0) * PSTRIDE + b]; P *= (a1 & 1) ? (1.f - pv) : pv;
            pv = (float)sProb[(9 + a1) * PSTRIDE + b]; P *= (a2 & 1) ? (1.f - pv) : pv;
            pv = (float)sProb[(13 + a2) * PSTRIDE + b];P *= (sl & 1) ? (1.f - pv) : pv;
            sP0[sl * 128 + b] = P;
        }
    }

    // ---------- output accumulators ----------
    floatx4 O[2][4];
    #pragma unroll
    for (int m = 0; m < 2; ++m)
        #pragma unroll
        for (int nt = 0; nt < 4; ++nt) { O[m][nt][0]=0.f; O[m][nt][1]=0.f; O[m][nt][2]=0.f; O[m][nt][3]=0.f; }

    // ---------- main loop over 16 subtrees of 64 leaves ----------
    for (int sl = 0; sl < 16; ++sl) {
        const int s = (g << 4) + sl;     // global subtree id at depth 10 (0..1023)
        __syncthreads();                 // prev-iter readers of sB/sV done

        // stage kdiff for 63 subtree nodes (+zero row 63) and V^T for 64 leaves
        {
            const int j = tid >> 2, part = tid & 3;
            int gidx = 0; bool valid = false;
            if (j < 63) {
                int u = j + 1;
                int f = 31 - __builtin_clz(u);
                int i = u - (1 << f);
                valid = true; gidx = ((1 << (10 + f)) - 1) + (s << f) + i;
            }
            store_kdiff(sB, tkey, j, part, gidx, valid);

            const int l = j;  // leaf 0..63
            const floatx4* vp = (const floatx4*)(tval + ((size_t)(s * 64 + l)) * 64);
            #pragma unroll
            for (int t = 0; t < 4; ++t) {
                floatx4 f = vp[part * 4 + t];
                #pragma unroll
                for (int e = 0; e < 4; ++e)
                    sV[(part * 16 + t * 4 + e) * 72 + l] = (_Float16)f[e];
            }
        }
        __syncthreads();

        // GEMM1: logit diffs D[b][j]
        floatx4 acc[2][4];
        #pragma unroll
        for (int m = 0; m < 2; ++m)
            #pragma unroll
            for (int nt = 0; nt < 4; ++nt) { acc[m][nt][0]=0.f; acc[m][nt][1]=0.f; acc[m][nt][2]=0.f; acc[m][nt][3]=0.f; }
        #pragma unroll
        for (int nt = 0; nt < 4; ++nt)
            #pragma unroll
            for (int kt = 0; kt < 2; ++kt) {
                half8 bf = *(const half8*)(sB + (16 * nt + lm) * 72 + 32 * kt + 8 * quad);
                acc[0][nt] = mfma16(qA[0][kt], bf, acc[0][nt]);
                acc[1][nt] = mfma16(qA[1][kt], bf, acc[1][nt]);
            }
        __syncthreads();

        // sigmoid -> node probs sProb[node][b] (fp16)
        #pragma unroll
        for (int m = 0; m < 2; ++m)
            #pragma unroll
            for (int nt = 0; nt < 4; ++nt) {
                half4v ph;
                #pragma unroll
                for (int r = 0; r < 4; ++r) ph[r] = (_Float16)sigmf(acc[m][nt][r]);
                *(half4v*)(sProb + (16 * nt + lm) * PSTRIDE + 32 * w + 16 * m + 4 * quad) = ph;
            }
        __syncthreads();

        // leaf probabilities: hierarchical product down 6 levels -> sA[b][l] fp16
        {
            const int b = tid & 127, h2 = tid >> 7;
            const float P0v = sP0[sl * 128 + b];
            #pragma unroll
            for (int qi = 0; qi < 2; ++qi) {
                const int qq = 2 * h2 + qi;
                float p0 = (float)sProb[0 * PSTRIDE + b];
                float p1 = (float)sProb[(1 + (qq >> 1)) * PSTRIDE + b];
                float P2 = P0v * (((qq >> 1) & 1) ? (1.f - p0) : p0)
                               * ((qq & 1) ? (1.f - p1) : p1);
                float p2 = (float)sProb[(3 + qq) * PSTRIDE + b];
                float A3[2]; A3[0] = P2 * p2; A3[1] = P2 * (1.f - p2);
                float A4[4];
                #pragma unroll
                for (int c = 0; c < 2; ++c) {
                    float pv = (float)sProb[(7 + 2 * qq + c) * PSTRIDE + b];
                    A4[2 * c] = A3[c] * pv; A4[2 * c + 1] = A3[c] * (1.f - pv);
                }
                float A5[8];
                #pragma unroll
                for (int n = 0; n < 4; ++n) {
                    float pv = (float)sProb[(15 + 4 * qq + n) * PSTRIDE + b];
                    A5[2 * n] = A4[n] * pv; A5[2 * n + 1] = A4[n] * (1.f - pv);
                }
                half8 lo, hi;
                #pragma unroll
                for (int n = 0; n < 8; ++n) {
                    float pv = (float)sProb[(31 + 8 * qq + n) * PSTRIDE + b];
                    float e0 = A5[n] * pv;
                    float e1 = A5[n] * (1.f - pv);
                    if (n < 4) { lo[2 * n] = (_Float16)e0; lo[2 * n + 1] = (_Float16)e1; }
                    else       { hi[2 * (n - 4)] = (_Float16)e0; hi[2 * (n - 4) + 1] = (_Float16)e1; }
                }
                *(half8*)(sA + b * 72 + 16 * qq)     = lo;
                *(half8*)(sA + b * 72 + 16 * qq + 8) = hi;
            }
        }
        __syncthreads();

        // GEMM2: O += P(b,l) @ V(l,v)
        {
            half8 af[2][2];
            #pragma unroll
            for (int m = 0; m < 2; ++m)
                #pragma unroll
                for (int kt = 0; kt < 2; ++kt)
                    af[m][kt] = *(const half8*)(sA + (32 * w + 16 * m + lm) * 72 + 32 * kt + 8 * quad);
            #pragma unroll
            for (int nt = 0; nt < 4; ++nt)
                #pragma unroll
                for (int kt = 0; kt < 2; ++kt) {
                    half8 bf = *(const half8*)(sV + (16 * nt + lm) * 72 + 32 * kt + 8 * quad);
                    O[0][nt] = mfma16(af[0][kt], bf, O[0][nt]);
                    O[1][nt] = mfma16(af[1][kt], bf, O[1][nt]);
                }
        }
    }

    // ---------- epilogue ----------
    if (!use_atomic) {
        #pragma unroll
        for (int m = 0; m < 2; ++m)
            #pragma unroll
            for (int nt = 0; nt < 4; ++nt) {
                const int brow = tb * 128 + 32 * w + 16 * m + 4 * quad;
                const int v = 16 * nt + lm;
                const size_t base = ((size_t)g * 2048 + brow) * 64 + v;
                #pragma unroll
                for (int r = 0; r < 4; ++r)
                    outp[base + (size_t)r * 64] = O[m][nt][r];
            }
    } else {
        #pragma unroll
        for (int m = 0; m < 2; ++m)
            #pragma unroll
            for (int nt = 0; nt < 4; ++nt) {
                const int brow = tb * 128 + 32 * w + 16 * m + 4 * quad;
                const int v = 16 * nt + lm;
                #pragma unroll
                for (int r = 0; r < 4; ++r)
                    atomicAdd(&outp[(size_t)(brow + r) * 64 + v], O[m][nt][r]);
            }
    }
}

// out[b][v] = sum over 64 group partials
__global__ __launch_bounds__(256)
void tree_reduce(const float* __restrict__ part, float* __restrict__ outp)
{
    const int idx = blockIdx.x * 256 + threadIdx.x;  // 0..131071
    float s = 0.f;
    #pragma unroll 8
    for (int gg = 0; gg < 64; ++gg)
        s += part[(size_t)gg * 131072 + idx];
    outp[idx] = s;
}

extern "C" void kernel_launch(void* const* d_in, const int* in_sizes, int n_in,
                              void* d_out, int out_size, void* d_ws, size_t ws_size,
                              hipStream_t stream)
{
    const float* q  = (const float*)d_in[0];
    const float* tk = (const float*)d_in[1];
    const float* tv = (const float*)d_in[2];
    float* outp = (float*)d_out;

    const size_t need = (size_t)64 * 2048 * 64 * sizeof(float);  // 33.5 MB partials
    if (ws_size >= need) {
        tree_attn<<<dim3(1024), dim3(256), 0, stream>>>(q, tk, tv, (float*)d_ws, 0);
        tree_reduce<<<dim3(512), dim3(256), 0, stream>>>((const float*)d_ws, outp);
    } else {
        hipMemsetAsync(d_out, 0, (size_t)2048 * 64 * sizeof(float), stream);
        tree_attn<<<dim3(1024), dim3(256), 0, stream>>>(q, tk, tv, outp, 1);
    }
}